// Round 5
// baseline (302.936 us; speedup 1.0000x reference)
//
#include <hip/hip_runtime.h>
#include <hip/hip_bf16.h>

typedef unsigned short ushort_t;
typedef unsigned int u32;
typedef __attribute__((ext_vector_type(8))) short bf16x8;
typedef __attribute__((ext_vector_type(4))) float f32x4;

#define NB 128
#define PP 200
#define KK 60
#define NN (NB*PP)      // 25600
#define HH 64

// d_out is FLOAT32. Offsets in f32 elements, return order: out, pos, batch, edge(src,dst)
#define OUT_OFF   0
#define POS_OFF   (NN*HH)             // 1638400
#define BATCH_OFF (POS_OFF + NN*3)    // 1715200
#define ESRC_OFF  (BATCH_OFF + NN)    // 1740800
#define EDST_OFF  (ESRC_OFF + NN*KK)  // 3276800

__device__ __forceinline__ ushort_t f2bf(float f) {
    __hip_bfloat16 h = __float2bfloat16(f);   // RNE
    ushort_t u; __builtin_memcpy(&u, &h, 2); return u;
}

// ---------------------------------------------------------------------------
// Kernel 0: passthrough outputs (pos copy, batch int -> float)
// ---------------------------------------------------------------------------
__global__ __launch_bounds__(256) void misc_kernel(const float* __restrict__ pos,
                                                   const int* __restrict__ batch,
                                                   float* __restrict__ out) {
    int gid = blockIdx.x * 256 + threadIdx.x;
    if (gid < NN * 3) out[POS_OFF + gid] = pos[gid];
    if (gid < NN)     out[BATCH_OFF + gid] = (float)batch[gid];
}

// ---------------------------------------------------------------------------
// Kernel 1: top-60 KNN per target (sorted by d2, ~ref order).
// One wave per target; u32 key = (f32bits(d2) & ~0xFF) | j (d2>=0 so bit order
// = value order; low byte = local id, tie -> lower index; 8 dropped mantissa
// bits only perturb near-ties, harmless under the 512 absmax threshold).
// Writes ESRC final; stashes local j into EDST as an f32 temp (exact).
// ---------------------------------------------------------------------------
__global__ __launch_bounds__(256) void knn_kernel(const float* __restrict__ pos,
                                                  float* __restrict__ out) {
    __shared__ float ps[PP * 3];
    int tid = threadIdx.x;
    int blk = blockIdx.x;
    int e = blk / 50, g = blk % 50;
    if (tid < PP) {
        int gi = (e * PP + tid) * 3;
        ps[tid*3+0] = pos[gi+0];
        ps[tid*3+1] = pos[gi+1];
        ps[tid*3+2] = pos[gi+2];
    }
    __syncthreads();

    int lane = tid & 63, wv = tid >> 6;
    int p = g * 4 + wv;          // local target id 0..199
    int i = e * PP + p;          // global target id
    float tx = ps[p*3], ty = ps[p*3+1], tz = ps[p*3+2];

    u32 key[4];
    #pragma unroll
    for (int q = 0; q < 4; ++q) {
        int j = lane + q * 64;
        u32 kv = 0xFFFFFFFFu;
        if (j < PP && j != p) {
            float dx = ps[j*3]   - tx;
            float dy = ps[j*3+1] - ty;
            float dz = ps[j*3+2] - tz;
            float d2 = dx*dx + dy*dy + dz*dz;
            kv = (__float_as_uint(d2) & 0xFFFFFF00u) | (u32)j;
        }
        key[q] = kv;
    }
    u32 lmin = min(min(key[0], key[1]), min(key[2], key[3]));
    u32 jsel = 0;

    for (int k = 0; k < KK; ++k) {
        u32 wmin = lmin;
        #pragma unroll
        for (int off = 32; off > 0; off >>= 1)
            wmin = min(wmin, (u32)__shfl_xor((int)wmin, off, 64));
        if (lane == k) jsel = wmin & 0xFFu;        // low byte = local index j
        if (lmin == wmin) {                        // unique owner
            #pragma unroll
            for (int q = 0; q < 4; ++q) if (key[q] == wmin) key[q] = 0xFFFFFFFFu;
            lmin = min(min(key[0], key[1]), min(key[2], key[3]));
        }
    }

    if (lane < KK) {
        int eidx = i * KK + lane;
        out[ESRC_OFF + eidx] = (float)(e * PP + (int)jsel);  // final
        out[EDST_OFF + eidx] = (float)jsel;                  // TEMP: local j (exact)
    }
}

// ---------------------------------------------------------------------------
// Kernel 2: fused message-MLP + max aggregation. Reads local j from the EDST
// temp slot, overwrites EDST with its final value (float)i. No workspace.
// Per target: 64-row tile (rows 0..59 = neighbors, 60 = self, 61..63 masked).
// Layer1 (7->64) f32 VALU -> LDS in MFMA-A-fragment order (bf16);
// Layer2 (64->64) mfma_f32_16x16x32_bf16, W2 B-frags in registers; masked max.
// ---------------------------------------------------------------------------
__global__ __launch_bounds__(256) void mlp_kernel(const float* __restrict__ x,
                                                  const float* __restrict__ pos,
                                                  const float* __restrict__ W1,
                                                  const float* __restrict__ b1,
                                                  const float* __restrict__ W2,
                                                  const float* __restrict__ b2,
                                                  float* __restrict__ out) {
    // A-fragment layout [mtile(4)][kstep(2)][lane(64)] of bf16x8 (16B aligned)
    __shared__ bf16x8 h1fv[512];
    __shared__ float w1t[64 * 8];    // [h][0..3]=W1[0..3][h], [4..6]=W1[4..6][h], [7]=b1[h]
    __shared__ float b2s[64];
    __shared__ float part[4][64];

    int tid = threadIdx.x, lane = tid & 63, wv = tid >> 6;

    for (int idx = tid; idx < 512; idx += 256) {
        int h = idx >> 3, f = idx & 7;
        w1t[idx] = (f < 7) ? W1[f * 64 + h] : b1[h];
    }
    if (tid < 64) b2s[tid] = b2[tid];

    // Preload W2 B-fragments: B[k = s*32 + (lane>>4)*8 + j][n = t*16 + (lane&15)]
    bf16x8 bfr[4][2];
    #pragma unroll
    for (int t = 0; t < 4; ++t)
        #pragma unroll
        for (int s = 0; s < 2; ++s)
            #pragma unroll
            for (int j = 0; j < 8; ++j)
                bfr[t][s][j] = (short)f2bf(W2[(s*32 + (lane>>4)*8 + j) * 64 + t*16 + (lane&15)]);
    __syncthreads();

    int r  = tid >> 2;           // edge row 0..63
    int hb = (tid & 3) * 16;     // k-offset this thread fills
    int mt = r >> 4, rl = r & 15;
    int s_ = hb >> 5;
    int q0 = (hb >> 3) & 3;      // 0 or 2

    for (int rep = 0; rep < 8; ++rep) {
        int i = blockIdx.x * 8 + rep;
        int e_base = (i / PP) * PP;

        bf16x8 ga = (bf16x8)0, gb = (bf16x8)0;
        if (r <= KK) {
            int src = i;
            if (r < KK) {
                int j = (int)out[EDST_OFF + i * KK + r];   // temp: j in [0,199], exact
                src = e_base + j;
            }
            float x0 = x[src*4+0], x1 = x[src*4+1];
            float x2 = x[src*4+2], x3 = x[src*4+3];
            float rx = 0.f, ry = 0.f, rz = 0.f;
            if (r < KK) {
                rx = pos[src*3+0] - pos[i*3+0];
                ry = pos[src*3+1] - pos[i*3+1];
                rz = pos[src*3+2] - pos[i*3+2];
            }
            #pragma unroll
            for (int jj = 0; jj < 16; ++jj) {
                int h = hb + jj;
                f32x4 wa = *reinterpret_cast<f32x4*>(&w1t[h * 8]);
                f32x4 wb = *reinterpret_cast<f32x4*>(&w1t[h * 8 + 4]);
                float v = wb[3];
                v = fmaf(x0, wa[0], v); v = fmaf(x1, wa[1], v);
                v = fmaf(x2, wa[2], v); v = fmaf(x3, wa[3], v);
                v = fmaf(rx, wb[0], v); v = fmaf(ry, wb[1], v);
                v = fmaf(rz, wb[2], v);
                v = fmaxf(v, 0.f);                 // relu layer 1
                ushort_t bits = f2bf(v);
                if (jj < 8) ga[jj] = (short)bits; else gb[jj - 8] = (short)bits;
            }
        }
        h1fv[(mt*2 + s_)*64 + q0*16 + rl]     = ga;
        h1fv[(mt*2 + s_)*64 + (q0+1)*16 + rl] = gb;
        __syncthreads();

        // All temp reads of EDST[i*KK + *] are done; write final value (float).
        if (tid < KK) out[EDST_OFF + i * KK + tid] = (float)i;

        f32x4 acc[4];
        #pragma unroll
        for (int t = 0; t < 4; ++t) acc[t] = (f32x4)0.f;
        #pragma unroll
        for (int s = 0; s < 2; ++s) {
            bf16x8 af = h1fv[(wv*2 + s)*64 + lane];
            #pragma unroll
            for (int t = 0; t < 4; ++t)
                acc[t] = __builtin_amdgcn_mfma_f32_16x16x32_bf16(af, bfr[t][s], acc[t], 0, 0, 0);
        }

        // epilogue: +b2, relu, masked max over edge rows
        #pragma unroll
        for (int t = 0; t < 4; ++t) {
            float m = 0.f;   // real values >= 0 after relu, 0 is a safe identity
            #pragma unroll
            for (int reg = 0; reg < 4; ++reg) {
                int row = wv*16 + (lane >> 4)*4 + reg;
                float val = fmaxf(acc[t][reg] + b2s[t*16 + (lane & 15)], 0.f);
                if (row > KK) val = 0.f;           // mask padding rows 61..63
                m = fmaxf(m, val);
            }
            m = fmaxf(m, __shfl_xor(m, 16, 64));
            m = fmaxf(m, __shfl_xor(m, 32, 64));
            if (lane < 16) part[wv][t*16 + lane] = m;
        }
        __syncthreads();
        if (tid < 64) {
            float v = fmaxf(fmaxf(part[0][tid], part[1][tid]),
                            fmaxf(part[2][tid], part[3][tid]));
            out[OUT_OFF + i*64 + tid] = v;         // float32 store
        }
        __syncthreads();
    }
}

// ---------------------------------------------------------------------------
extern "C" void kernel_launch(void* const* d_in, const int* in_sizes, int n_in,
                              void* d_out, int out_size, void* d_ws, size_t ws_size,
                              hipStream_t stream) {
    const float* x     = (const float*)d_in[0];
    const float* pos   = (const float*)d_in[1];
    const int*   batch = (const int*)d_in[2];
    const float* W1    = (const float*)d_in[3];
    const float* b1    = (const float*)d_in[4];
    const float* W2    = (const float*)d_in[5];
    const float* b2    = (const float*)d_in[6];
    float* out = (float*)d_out;
    (void)d_ws; (void)ws_size; (void)in_sizes; (void)n_in; (void)out_size;

    misc_kernel<<<dim3((NN*3 + 255)/256), dim3(256), 0, stream>>>(pos, batch, out);
    knn_kernel<<<dim3(NB * 50), dim3(256), 0, stream>>>(pos, out);
    mlp_kernel<<<dim3(NN / 8), dim3(256), 0, stream>>>(x, pos, W1, b1, W2, b2, out);
}

// Round 6
// 188.529 us; speedup vs baseline: 1.6068x; 1.6068x over previous
//
#include <hip/hip_runtime.h>
#include <hip/hip_bf16.h>

typedef unsigned short ushort_t;
typedef unsigned int u32;
typedef __attribute__((ext_vector_type(8))) short bf16x8;
typedef __attribute__((ext_vector_type(4))) float f32x4;
typedef __attribute__((ext_vector_type(4))) u32 u32x4;

#define NB 128
#define PP 200
#define KK 60
#define NN (NB*PP)      // 25600
#define HH 64

// d_out is FLOAT32. Offsets in f32 elements, return order: out, pos, batch, edge(src,dst)
#define OUT_OFF   0
#define POS_OFF   (NN*HH)             // 1638400
#define BATCH_OFF (POS_OFF + NN*3)    // 1715200
#define ESRC_OFF  (BATCH_OFF + NN)    // 1740800
#define EDST_OFF  (ESRC_OFF + NN*KK)  // 3276800

__device__ __forceinline__ ushort_t f2bf(float f) {
    __hip_bfloat16 h = __float2bfloat16(f);   // RNE
    ushort_t u; __builtin_memcpy(&u, &h, 2); return u;
}
__device__ __forceinline__ u32 pack2bf(float a, float b) {
    return (u32)f2bf(a) | ((u32)f2bf(b) << 16);
}

// ---------------------------------------------------------------------------
// Kernel 1: KNN via rank selection (shuffle-free) + pos/batch passthrough.
// One wave per target. key = (f32bits(d2) & ~0xFF) | j  -> unique keys, bit
// order = d2 order, tie -> lower index. rank_j = #{keys < key_j}; winners
// (rank<60) scatter directly to their sorted output slot. Ranks are a
// bijection onto 0..59 => every ESRC/EDST slot written exactly once.
// ESRC final; EDST carries local j as a temp for the MLP kernel.
// ---------------------------------------------------------------------------
__global__ __launch_bounds__(256) void knn_kernel(const float* __restrict__ pos,
                                                  float* __restrict__ out) {
    __shared__ alignas(16) float ps[PP * 3];
    __shared__ alignas(16) u32 keys[4 * 256];
    int tid = threadIdx.x, blk = blockIdx.x;
    int e = blk / 50, g = blk % 50;
    if (tid < 150)
        ((f32x4*)ps)[tid] = ((const f32x4*)pos)[e * 150 + tid];
    __syncthreads();

    // passthrough: this block's 4 targets' pos rows + batch ids
    if (tid < 12) {
        int t_ = tid / 3, c = tid % 3;
        out[POS_OFF + (e * PP + g * 4 + t_) * 3 + c] = ps[(g * 4 + t_) * 3 + c];
    }
    if (tid < 4) out[BATCH_OFF + e * PP + g * 4 + tid] = (float)e;

    int lane = tid & 63, wv = tid >> 6;
    int p = g * 4 + wv;          // local target id
    int i = e * PP + p;          // global target id
    float tx = ps[p*3], ty = ps[p*3+1], tz = ps[p*3+2];

    u32 key[4];
    #pragma unroll
    for (int q = 0; q < 4; ++q) {
        int j = lane + q * 64;
        u32 kv = 0xFFFFFFFFu;
        if (j < PP && j != p) {
            float dx = ps[j*3]   - tx;
            float dy = ps[j*3+1] - ty;
            float dz = ps[j*3+2] - tz;
            float d2 = dx*dx + dy*dy + dz*dz;
            kv = (__float_as_uint(d2) & 0xFFFFFF00u) | (u32)j;
        }
        key[q] = kv;
        keys[wv * 256 + q * 64 + lane] = kv;   // bank = lane%32 -> 2-way, free
    }
    // (compiler inserts lgkmcnt wait; keys are wave-private, no barrier)

    u32 rk[4] = {0, 0, 0, 0};
    for (int it = 0; it < 50; ++it) {          // exactly 200 real candidates
        u32x4 kv4 = *(const u32x4*)&keys[wv * 256 + it * 4];  // broadcast read
        #pragma unroll
        for (int m = 0; m < 4; ++m) {
            rk[0] += (kv4[m] < key[0]);
            rk[1] += (kv4[m] < key[1]);
            rk[2] += (kv4[m] < key[2]);
            rk[3] += (kv4[m] < key[3]);
        }
    }
    #pragma unroll
    for (int q = 0; q < 4; ++q) {
        if (rk[q] < KK) {                      // invalid keys rank >= 199
            int j = (int)(key[q] & 0xFFu);
            int eidx = i * KK + (int)rk[q];
            out[ESRC_OFF + eidx] = (float)(e * PP + j);  // final
            out[EDST_OFF + eidx] = (float)j;             // TEMP: local j
        }
    }
}

// ---------------------------------------------------------------------------
// Kernel 2: fused message-MLP + max aggregation, both layers on MFMA.
// One wave per target (2 targets/wave sequentially, 8 per block, one event
// per block). Layer 1 computed TRANSPOSED: A = W1'^T (b1 baked in feature
// slot 7), B = messages^T => C holds h1^T. C-frags convert to layer-2
// A-frags via a conflict-free intra-wave LDS dword permute (no barrier).
// Layer 2: standard A(h1) x B(W2), epilogue +b2/relu/masked-max in-wave.
// ---------------------------------------------------------------------------
__global__ __launch_bounds__(256) void mlp_kernel(const float* __restrict__ x,
                                                  const float* __restrict__ pos,
                                                  const float* __restrict__ W1,
                                                  const float* __restrict__ b1,
                                                  const float* __restrict__ W2,
                                                  const float* __restrict__ b2,
                                                  float* __restrict__ out) {
    __shared__ alignas(16) float xs[PP * 4];    // event x rows
    __shared__ alignas(16) float psl[PP * 3];   // event pos rows
    __shared__ alignas(16) u32 af[4 * 512];     // per-wave A-frag shuffle region

    int tid = threadIdx.x, blk = blockIdx.x;
    int e = blk / 25;
    int lane = tid & 63, wv = tid >> 6;
    int lo = lane & 15, hi = lane >> 4;

    if (tid < 200) ((f32x4*)xs)[tid]  = ((const f32x4*)x)[e * PP + tid];
    if (tid < 150) ((f32x4*)psl)[tid] = ((const f32x4*)pos)[e * 150 + tid];

    // W1'^T A-frags: lane holds A[m=h=th*16+lo][k=hi*8+j]; only k<8 real.
    bf16x8 w1f[4];
    #pragma unroll
    for (int th = 0; th < 4; ++th) {
        bf16x8 v = (bf16x8)0;
        if (hi == 0) {
            #pragma unroll
            for (int j = 0; j < 8; ++j) {
                float w = (j < 7) ? W1[j * 64 + th * 16 + lo] : b1[th * 16 + lo];
                v[j] = (short)f2bf(w);
            }
        }
        w1f[th] = v;
    }
    // W2 B-frags: B[k=s*32+hi*8+j][n=t*16+lo]
    bf16x8 bfr[4][2];
    #pragma unroll
    for (int t = 0; t < 4; ++t)
        #pragma unroll
        for (int s = 0; s < 2; ++s)
            #pragma unroll
            for (int j = 0; j < 8; ++j)
                bfr[t][s][j] = (short)f2bf(W2[(s*32 + hi*8 + j) * 64 + t*16 + lo]);
    float b2v[4];
    #pragma unroll
    for (int t = 0; t < 4; ++t) b2v[t] = b2[t * 16 + lo];
    __syncthreads();

    const int afb = wv * 512;
    for (int tl = 0; tl < 2; ++tl) {
        int i = blk * 8 + wv * 2 + tl;
        int pl = i - e * PP;                    // local target id
        float px = psl[pl*3], py = psl[pl*3+1], pz = psl[pl*3+2];
        float runmax[4] = {0.f, 0.f, 0.f, 0.f};

        #pragma unroll
        for (int rt = 0; rt < 4; ++rt) {
            // message B-frag: B[k=f][n=row&15]; rows rt*16+lo, lanes 0-15 only
            bf16x8 mf = (bf16x8)0;
            if (hi == 0) {
                int r = rt * 16 + lo;
                if (r <= KK) {
                    int jloc = (r < KK) ? (int)out[EDST_OFF + i * KK + r] : pl;
                    f32x4 xv = ((const f32x4*)xs)[jloc];
                    float rx = 0.f, ry = 0.f, rz = 0.f;
                    if (r < KK) {
                        rx = psl[jloc*3]   - px;
                        ry = psl[jloc*3+1] - py;
                        rz = psl[jloc*3+2] - pz;
                    }
                    mf[0] = (short)f2bf(xv[0]); mf[1] = (short)f2bf(xv[1]);
                    mf[2] = (short)f2bf(xv[2]); mf[3] = (short)f2bf(xv[3]);
                    mf[4] = (short)f2bf(rx);    mf[5] = (short)f2bf(ry);
                    mf[6] = (short)f2bf(rz);    mf[7] = (short)f2bf(1.0f);
                }
            }
            // Layer 1: c1[th] = h1^T tile: (m=h=th*16+hi*4+reg, n=row=rt*16+lo)
            f32x4 c1[4];
            #pragma unroll
            for (int th = 0; th < 4; ++th)
                c1[th] = __builtin_amdgcn_mfma_f32_16x16x32_bf16(w1f[th], mf,
                                                                 (f32x4)0.f, 0, 0, 0);
            // relu + pack + conflict-free permute into layer-2 A-frag layout
            #pragma unroll
            for (int th = 0; th < 4; ++th) {
                u32 pk0 = pack2bf(fmaxf(c1[th][0], 0.f), fmaxf(c1[th][1], 0.f));
                u32 pk1 = pack2bf(fmaxf(c1[th][2], 0.f), fmaxf(c1[th][3], 0.f));
                int s = th >> 1;
                int dlane = lo + (((th & 1) * 2 + (hi >> 1)) << 4);
                int dbase = (hi & 1) * 2;
                af[afb + s * 256 + (dbase + 0) * 64 + dlane] = pk0;  // banks 2-way
                af[afb + s * 256 + (dbase + 1) * 64 + dlane] = pk1;
            }
            // Layer 2: A[m=row&15=lo][k=s*32+hi*8+j]
            f32x4 acc[4];
            #pragma unroll
            for (int t = 0; t < 4; ++t) acc[t] = (f32x4)0.f;
            #pragma unroll
            for (int s = 0; s < 2; ++s) {
                union { u32 w[4]; bf16x8 v; } u;
                #pragma unroll
                for (int d = 0; d < 4; ++d)
                    u.w[d] = af[afb + s * 256 + d * 64 + lane];  // banks 2-way
                #pragma unroll
                for (int t = 0; t < 4; ++t)
                    acc[t] = __builtin_amdgcn_mfma_f32_16x16x32_bf16(u.v, bfr[t][s],
                                                                     acc[t], 0, 0, 0);
            }
            // epilogue fold: +b2, relu, mask pad rows, running max
            #pragma unroll
            for (int t = 0; t < 4; ++t) {
                #pragma unroll
                for (int reg = 0; reg < 4; ++reg) {
                    int r = rt * 16 + hi * 4 + reg;
                    float val = fmaxf(acc[t][reg] + b2v[t], 0.f);
                    if (r > KK) val = 0.f;
                    runmax[t] = fmaxf(runmax[t], val);
                }
            }
        }
        // cross-hi-group max (columns preserved under xor 16/32)
        #pragma unroll
        for (int t = 0; t < 4; ++t) {
            runmax[t] = fmaxf(runmax[t], __shfl_xor(runmax[t], 16, 64));
            runmax[t] = fmaxf(runmax[t], __shfl_xor(runmax[t], 32, 64));
        }
        if (lane < 16) {
            #pragma unroll
            for (int t = 0; t < 4; ++t)
                out[OUT_OFF + i * 64 + t * 16 + lane] = runmax[t];
        }
        // all EDST temp reads for target i are done (same wave): finalize
        if (lane < KK) out[EDST_OFF + i * KK + lane] = (float)i;
    }
}

// ---------------------------------------------------------------------------
extern "C" void kernel_launch(void* const* d_in, const int* in_sizes, int n_in,
                              void* d_out, int out_size, void* d_ws, size_t ws_size,
                              hipStream_t stream) {
    const float* x     = (const float*)d_in[0];
    const float* pos   = (const float*)d_in[1];
    const float* W1    = (const float*)d_in[3];
    const float* b1    = (const float*)d_in[4];
    const float* W2    = (const float*)d_in[5];
    const float* b2    = (const float*)d_in[6];
    float* out = (float*)d_out;
    (void)d_ws; (void)ws_size; (void)in_sizes; (void)n_in; (void)out_size;

    knn_kernel<<<dim3(NB * 50), dim3(256), 0, stream>>>(pos, out);
    mlp_kernel<<<dim3(NN / 8), dim3(256), 0, stream>>>(x, pos, W1, b1, W2, b2, out);
}